// Round 1
// 415.703 us; speedup vs baseline: 1.0688x; 1.0688x over previous
//
#include <hip/hip_runtime.h>

typedef unsigned short u16;
typedef __bf16 bf16x8 __attribute__((ext_vector_type(8)));
typedef unsigned short u16x8 __attribute__((ext_vector_type(8)));
typedef unsigned short u16x4 __attribute__((ext_vector_type(4)));
typedef float f32x4 __attribute__((ext_vector_type(4)));

#define MFMA16(a, b, c) __builtin_amdgcn_mfma_f32_16x16x32_bf16(a, b, c, 0, 0, 0)

__device__ __forceinline__ u16 f2bf(float f) {
    union { float f; unsigned u; } v; v.f = f;
    unsigned r = v.u + 0x7fffu + ((v.u >> 16) & 1u);
    return (u16)(r >> 16);
}
__device__ __forceinline__ float bf2f(u16 u) {
    union { unsigned u; float f; } v; v.u = (unsigned)u << 16;
    return v.f;
}

// async global->LDS, 16B per lane. LDS dest is wave-uniform base + lane*16.
typedef __attribute__((address_space(1))) void GAS;
typedef __attribute__((address_space(3))) void LAS;
__device__ __forceinline__ void gload_lds16(const void* g, void* l) {
    __builtin_amdgcn_global_load_lds((GAS*)g, (LAS*)l, 16, 0, 0);
}

// ---------------------------------------------------------------------------
// Kernel 0: transpose-convert W (512x512 fp32, k-major) -> WT (n-major, k-contig) bf16
// ---------------------------------------------------------------------------
__global__ __launch_bounds__(256) void wtrans(const float* Wq, const float* Wk,
                                              const float* Wv, const float* Wo, u16* WT) {
    __shared__ float t[32][33];
    const int z = blockIdx.z;
    const float* W = (z == 0) ? Wq : (z == 1) ? Wk : (z == 2) ? Wv : Wo;
    u16* out = WT + (size_t)z * 512 * 512;
    const int tx = threadIdx.x, ty = threadIdx.y;
    const int k0 = blockIdx.y * 32, n0 = blockIdx.x * 32;
#pragma unroll
    for (int p = 0; p < 4; ++p)
        t[ty + 8 * p][tx] = W[(size_t)(k0 + ty + 8 * p) * 512 + n0 + tx];
    __syncthreads();
#pragma unroll
    for (int p = 0; p < 4; ++p) {
        const int n = n0 + ty + 8 * p;
        out[(size_t)n * 512 + k0 + tx] = f2bf(t[tx][ty + 8 * p]);
    }
}

// ---------------------------------------------------------------------------
// Kernel 1: convert q,k fp32 -> bf16 (row-major, same layout)
// ---------------------------------------------------------------------------
__global__ __launch_bounds__(256) void qkconv(const float* q, const float* k, u16* qb, u16* kb) {
    const size_t n4 = (size_t)8192 * 512 / 4;
    const size_t stride = (size_t)gridDim.x * 256;
    for (size_t i = (size_t)blockIdx.x * 256 + threadIdx.x; i < 2 * n4; i += stride) {
        const float4 v = (i < n4) ? ((const float4*)q)[i] : ((const float4*)k)[i - n4];
        u16x4 o;
        o[0] = f2bf(v.x); o[1] = f2bf(v.y); o[2] = f2bf(v.z); o[3] = f2bf(v.w);
        if (i < n4) ((u16x4*)qb)[i] = o; else ((u16x4*)kb)[i - n4] = o;
    }
}

// ---------------------------------------------------------------------------
// Kernel 1b: per-head transpose of vw: [B,L,H*64] bf16 -> vt [B*H][64 dk][1024 L]
// ---------------------------------------------------------------------------
__global__ __launch_bounds__(256) void vtrans(const u16* vw, u16* vt) {
    __shared__ u16 t[64][72];
    const int l0 = blockIdx.x * 64, h = blockIdx.y, b = blockIdx.z;
    const int tid = threadIdx.x;
    {
        const int r = tid >> 2, c16 = (tid & 3) * 16;
        const u16* src = vw + (size_t)(b * 1024 + l0 + r) * 512 + h * 64 + c16;
        *(u16x8*)(&t[r][c16])     = *(const u16x8*)(src);
        *(u16x8*)(&t[r][c16 + 8]) = *(const u16x8*)(src + 8);
    }
    __syncthreads();
    {
        const int dk = tid >> 2, lc = (tid & 3) * 16;
        u16x8 a0, a1;
#pragma unroll
        for (int e = 0; e < 8; ++e) { a0[e] = t[lc + e][dk]; a1[e] = t[lc + 8 + e][dk]; }
        u16* dst = vt + ((size_t)(b * 8 + h) * 64 + dk) * 1024 + l0 + lc;
        *(u16x8*)dst       = a0;
        *(u16x8*)(dst + 8) = a1;
    }
}

// ---------------------------------------------------------------------------
// GEMM core (all-bf16 inputs): C(8192 x 512) = A @ B + bias
// m97-style: global_load_lds dwordx4 staging into linear [128][64] LDS.
// ---------------------------------------------------------------------------
template <bool C_F32>
__device__ __forceinline__ void gemm_core(const u16* A, const u16* Bt,
                                          const float* bias, void* Cp,
                                          int bm, int bn) {
    __shared__ u16 As[128 * 64];
    __shared__ u16 Bs[128 * 64];
    const int tid  = threadIdx.x;
    const int lane = tid & 63;
    const int w    = tid >> 6;
    const int wm   = (w >> 1) * 64;
    const int wn   = (w & 1) * 64;
    const int col  = lane & 15;
    const int quad = lane >> 4;
    const int srow = lane >> 3;          // 0..7 within chunk
    const int scol = (lane & 7) * 8;     // u16 col within BK=64

    f32x4 acc[4][4] = {};

    for (int kt = 0; kt < 512; kt += 64) {
        __syncthreads();
#pragma unroll
        for (int p = 0; p < 4; ++p) {
            const int c  = w * 4 + p;        // 16 chunks of 1024B per tile
            const int gr = c * 8 + srow;
            gload_lds16(A  + (size_t)(bm * 128 + gr) * 512 + kt + scol, As + c * 512);
            gload_lds16(Bt + (size_t)(bn * 128 + gr) * 512 + kt + scol, Bs + c * 512);
        }
        __syncthreads();   // compiler drains vmcnt(0) here -> LDS tile ready
#pragma unroll
        for (int ks = 0; ks < 2; ++ks) {
            const int k0 = ks * 32 + quad * 8;
            bf16x8 af[4], bfr[4];
#pragma unroll
            for (int i = 0; i < 4; ++i)
                af[i] = __builtin_bit_cast(bf16x8, *(const u16x8*)(As + (wm + i * 16 + col) * 64 + k0));
#pragma unroll
            for (int j = 0; j < 4; ++j)
                bfr[j] = __builtin_bit_cast(bf16x8, *(const u16x8*)(Bs + (wn + j * 16 + col) * 64 + k0));
#pragma unroll
            for (int i = 0; i < 4; ++i)
#pragma unroll
                for (int j = 0; j < 4; ++j)
                    acc[i][j] = MFMA16(af[i], bfr[j], acc[i][j]);
        }
    }
#pragma unroll
    for (int j = 0; j < 4; ++j) {
        const int gn = bn * 128 + wn + j * 16 + col;
        const float bv = bias[gn];
#pragma unroll
        for (int i = 0; i < 4; ++i) {
#pragma unroll
            for (int r = 0; r < 4; ++r) {
                const int gm = bm * 128 + wm + i * 16 + quad * 4 + r;
                const float val = acc[i][j][r] + bv;
                if (C_F32) ((float*)Cp)[(size_t)gm * 512 + gn] = val;
                else       ((u16*)Cp)[(size_t)gm * 512 + gn]   = f2bf(val);
            }
        }
    }
}

// grid (64,4,3): z=0 qw=qb@Wq+bq, z=1 kw=kb@Wk+bk, z=2 vw=qb@Wv+bv (reference bug)
__global__ __launch_bounds__(256, 3) void qkv_gemm(const u16* qb, const u16* kb, const u16* WT,
                                                   const float* bq, const float* bk, const float* bv,
                                                   u16* out) {
    const int z = blockIdx.z;
    const u16* A      = (z == 1) ? kb : qb;
    const u16* B      = WT + (size_t)z * 512 * 512;
    const float* bias = (z == 0) ? bq : (z == 1) ? bk : bv;
    u16* C            = out + (size_t)z * 8192 * 512;
    gemm_core<false>(A, B, bias, C, blockIdx.x, blockIdx.y);
}

__global__ __launch_bounds__(256, 3) void out_gemm(const u16* ctx, const u16* WoT,
                                                   const float* bo, float* out) {
    gemm_core<true>(ctx, WoT, bo, out, blockIdx.x, blockIdx.y);
}

// ---------------------------------------------------------------------------
// Kernel 2: attention. grid (8 qtiles, 64 bh), 512 threads (8 waves).
// Wave w owns 16 Q rows; Q fragments in registers. KVBLK=128, NT=8.
// V pre-transposed globally (vt[bh][dk][L]) -> vectorized LDS staging.
// T14 staging: next-tile global loads issued AFTER the LDS-ready barrier so
// they stay in flight across the whole compute phase (drained at next top
// barrier, where ds_write needs them anyway).
// ---------------------------------------------------------------------------
__global__ __launch_bounds__(512, 4) void attn_kernel(const u16* qw, const u16* kw, const u16* vt,
                                                      float* attn_out, u16* ctx) {
    __shared__ u16 Ks[128 * 72];       // [key][dk]   18432 B
    __shared__ u16 Vs[64 * 136];       // [dk][key]   17408 B
    __shared__ u16 Ps[8][16 * 136];    // per-wave [qrow][key] 34816 B  (total 70656 B)

    const int qt  = blockIdx.x;
    const int bh  = blockIdx.y;
    const int b   = bh >> 3, h = bh & 7;
    const int tid = threadIdx.x;
    const int lane = tid & 63, w = tid >> 6;
    const int col = lane & 15, quad = lane >> 4;
    const int wq  = w * 16;
    const float scale = 0.125f;

    const size_t headbase = (size_t)b * (1024 * 512) + (size_t)h * 64;
    const u16* vh = vt + (size_t)bh * (64 * 1024);

    // staging addressing
    const int krow = tid >> 2, koff = (tid & 3) * 16;   // 128 rows x 64 dk
    const int vrow = tid >> 3, voff = (tid & 7) * 16;   // 64 rows x 128 keys
    const u16* kbase = kw + headbase + (size_t)krow * 512 + koff;
    const u16* vbase = vh + (size_t)vrow * 1024 + voff;

    // Q fragment in registers (A-layout: row=lane&15, k=quad*8+j)
    bf16x8 qf[2];
    {
        const u16* qp = qw + headbase + (size_t)(qt * 128 + wq + col) * 512 + quad * 8;
        qf[0] = __builtin_bit_cast(bf16x8, *(const u16x8*)qp);
        qf[1] = __builtin_bit_cast(bf16x8, *(const u16x8*)(qp + 32));
    }

    float l_acc[4] = {0.f, 0.f, 0.f, 0.f};

    // ---------------- pass 1: row sumexp ----------------
    u16x8 rk0 = *(const u16x8*)kbase;
    u16x8 rk1 = *(const u16x8*)(kbase + 8);
    for (int kt = 0; kt < 8; ++kt) {
        __syncthreads();                       // waves done reading prev tile; loads drained
        *(u16x8*)(Ks + krow * 72 + koff)     = rk0;
        *(u16x8*)(Ks + krow * 72 + koff + 8) = rk1;
        __syncthreads();                       // tile visible
        if (kt < 7) {                          // prefetch next tile: in flight across compute
            const u16* kp = kbase + (size_t)(kt + 1) * (128 * 512);
            rk0 = *(const u16x8*)kp;
            rk1 = *(const u16x8*)(kp + 8);
        }
        f32x4 s[8] = {};
#pragma unroll
        for (int ks = 0; ks < 2; ++ks) {
            const int k0 = ks * 32 + quad * 8;
#pragma unroll
            for (int j = 0; j < 8; ++j) {
                const bf16x8 kf = __builtin_bit_cast(bf16x8,
                    *(const u16x8*)(Ks + (j * 16 + col) * 72 + k0));
                s[j] = MFMA16(qf[ks], kf, s[j]);
            }
        }
#pragma unroll
        for (int j = 0; j < 8; ++j)
#pragma unroll
            for (int r = 0; r < 4; ++r)
                l_acc[r] += __expf(s[j][r] * scale);
    }

    float rinv[4];
#pragma unroll
    for (int r = 0; r < 4; ++r) {
        float l = l_acc[r];
        l += __shfl_xor(l, 1); l += __shfl_xor(l, 2);
        l += __shfl_xor(l, 4); l += __shfl_xor(l, 8);
        rinv[r] = 1.0f / l;
    }

    f32x4 o[4] = {};

    // ---------------- pass 2 ----------------
    rk0 = *(const u16x8*)kbase;
    rk1 = *(const u16x8*)(kbase + 8);
    u16x8 rv0 = *(const u16x8*)vbase;
    u16x8 rv1 = *(const u16x8*)(vbase + 8);
    for (int kt = 0; kt < 8; ++kt) {
        __syncthreads();
        *(u16x8*)(Ks + krow * 72 + koff)      = rk0;
        *(u16x8*)(Ks + krow * 72 + koff + 8)  = rk1;
        *(u16x8*)(Vs + vrow * 136 + voff)     = rv0;
        *(u16x8*)(Vs + vrow * 136 + voff + 8) = rv1;
        __syncthreads();
        if (kt < 7) {
            const u16* kp = kbase + (size_t)(kt + 1) * (128 * 512);
            rk0 = *(const u16x8*)kp;
            rk1 = *(const u16x8*)(kp + 8);
            const u16* vp = vbase + (kt + 1) * 128;
            rv0 = *(const u16x8*)vp;
            rv1 = *(const u16x8*)(vp + 8);
        }
        u16* pw = &Ps[w][0];
#pragma unroll
        for (int half = 0; half < 2; ++half) {
            f32x4 s[4] = {};
#pragma unroll
            for (int ks = 0; ks < 2; ++ks) {
                const int k0 = ks * 32 + quad * 8;
#pragma unroll
                for (int j = 0; j < 4; ++j) {
                    const bf16x8 kf = __builtin_bit_cast(bf16x8,
                        *(const u16x8*)(Ks + (half * 64 + j * 16 + col) * 72 + k0));
                    s[j] = MFMA16(qf[ks], kf, s[j]);
                }
            }
            // normalized P (bf16) -> per-wave LDS (C-layout: row=quad*4+r, col=key)
#pragma unroll
            for (int j = 0; j < 4; ++j)
#pragma unroll
                for (int r = 0; r < 4; ++r) {
                    const float p = __expf(s[j][r] * scale) * rinv[r];
                    pw[(quad * 4 + r) * 136 + half * 64 + j * 16 + col] = f2bf(p);
                }
        }
        // coalesced attn stores: 16 rows x 128 keys fp32 per tile per wave
        {
            const int rl = lane >> 2, c0 = (lane & 3) * 4;
            float* ao = attn_out + ((size_t)bh * 1024 + (size_t)(qt * 128 + wq + rl)) * 1024
                        + (size_t)kt * 128 + c0;
#pragma unroll
            for (int it = 0; it < 8; ++it) {
                const u16x4 pv = *(const u16x4*)(pw + rl * 136 + it * 16 + c0);
                float4 f;
                f.x = bf2f(pv[0]); f.y = bf2f(pv[1]); f.z = bf2f(pv[2]); f.w = bf2f(pv[3]);
                *(float4*)(ao + it * 16) = f;
            }
        }
        // PV: o[m][dk] += P[m][key] * V[key][dk], 128 keys = 4 k-slices
#pragma unroll
        for (int ks = 0; ks < 4; ++ks) {
            const int k0 = ks * 32 + quad * 8;
            const bf16x8 pf = __builtin_bit_cast(bf16x8, *(const u16x8*)(pw + col * 136 + k0));
#pragma unroll
            for (int j = 0; j < 4; ++j) {
                const bf16x8 vf = __builtin_bit_cast(bf16x8,
                    *(const u16x8*)(Vs + (j * 16 + col) * 136 + k0));
                o[j] = MFMA16(pf, vf, o[j]);
            }
        }
    }

    // ctx (bf16) at head slice
#pragma unroll
    for (int j = 0; j < 4; ++j)
#pragma unroll
        for (int r = 0; r < 4; ++r) {
            const int qg = qt * 128 + wq + quad * 4 + r;
            ctx[(size_t)(b * 1024 + qg) * 512 + h * 64 + j * 16 + col] = f2bf(o[j][r]);
        }
}

// ---------------------------------------------------------------------------
extern "C" void kernel_launch(void* const* d_in, const int* in_sizes, int n_in,
                              void* d_out, int out_size, void* d_ws, size_t ws_size,
                              hipStream_t stream) {
    (void)in_sizes; (void)n_in; (void)out_size; (void)ws_size;
    const float* q  = (const float*)d_in[0];
    const float* k  = (const float*)d_in[1];
    // d_in[2] = v : unused (reference bug applies Wv to q)
    const float* Wq = (const float*)d_in[3];
    const float* bq = (const float*)d_in[4];
    const float* Wk = (const float*)d_in[5];
    const float* bk = (const float*)d_in[6];
    const float* Wv = (const float*)d_in[7];
    const float* bv = (const float*)d_in[8];
    const float* Wo = (const float*)d_in[9];
    const float* bo = (const float*)d_in[10];

    float* out  = (float*)d_out;                              // (8,1024,512)
    float* attn = (float*)d_out + (size_t)8 * 1024 * 512;     // (8,8,1024,1024)

    // workspace layout
    char* ws = (char*)d_ws;
    u16* WT  = (u16*)ws;                                       // 2 MB
    u16* qb  = (u16*)(ws + (size_t)2 * 1024 * 1024);           // 8 MB
    u16* kb  = qb + (size_t)8192 * 512;                        // 8 MB
    u16* qkv = kb + (size_t)8192 * 512;                        // 32 MB (qw,kw,vw,ctx)
    u16* qw  = qkv;
    u16* kw  = qkv + (size_t)8192 * 512;
    u16* vw  = qkv + (size_t)2 * 8192 * 512;
    u16* ctx = qkv + (size_t)3 * 8192 * 512;
    u16* vt  = qkv + (size_t)4 * 8192 * 512;                   // 8 MB transposed V

    wtrans     <<<dim3(16, 16, 4), dim3(32, 8), 0, stream>>>(Wq, Wk, Wv, Wo, WT);
    qkconv     <<<dim3(2048),      256,          0, stream>>>(q, k, qb, kb);
    qkv_gemm   <<<dim3(64, 4, 3),  256,          0, stream>>>(qb, kb, WT, bq, bk, bv, qkv);
    vtrans     <<<dim3(16, 8, 8),  256,          0, stream>>>(vw, vt);
    attn_kernel<<<dim3(8, 64),     512,          0, stream>>>(qw, kw, vt, attn, ctx);
    out_gemm   <<<dim3(64, 4),     256,          0, stream>>>(ctx, WT + (size_t)3 * 512 * 512, bo, out);
}

// Round 4
// 410.629 us; speedup vs baseline: 1.0820x; 1.0124x over previous
//
#include <hip/hip_runtime.h>

typedef unsigned short u16;
typedef __bf16 bf16x8 __attribute__((ext_vector_type(8)));
typedef unsigned short u16x8 __attribute__((ext_vector_type(8)));
typedef unsigned short u16x4 __attribute__((ext_vector_type(4)));
typedef float f32x4 __attribute__((ext_vector_type(4)));

#define MFMA16(a, b, c) __builtin_amdgcn_mfma_f32_16x16x32_bf16(a, b, c, 0, 0, 0)

__device__ __forceinline__ u16 f2bf(float f) {
    union { float f; unsigned u; } v; v.f = f;
    unsigned r = v.u + 0x7fffu + ((v.u >> 16) & 1u);
    return (u16)(r >> 16);
}
__device__ __forceinline__ float bf2f(u16 u) {
    union { unsigned u; float f; } v; v.u = (unsigned)u << 16;
    return v.f;
}
// native RNE cast (pairs into v_cvt_pk_bf16_f32)
__device__ __forceinline__ u16 bfc(float f) {
    return __builtin_bit_cast(u16, (__bf16)f);
}

// async global->LDS, 16B per lane. LDS dest is wave-uniform base + lane*16.
typedef __attribute__((address_space(1))) void GAS;
typedef __attribute__((address_space(3))) void LAS;
__device__ __forceinline__ void gload_lds16(const void* g, void* l) {
    __builtin_amdgcn_global_load_lds((GAS*)g, (LAS*)l, 16, 0, 0);
}

// ---------------------------------------------------------------------------
// Kernel 0: transpose-convert W (512x512 fp32, k-major) -> WT (n-major, k-contig) bf16
// ---------------------------------------------------------------------------
__global__ __launch_bounds__(256) void wtrans(const float* Wq, const float* Wk,
                                              const float* Wv, const float* Wo, u16* WT) {
    __shared__ float t[32][33];
    const int z = blockIdx.z;
    const float* W = (z == 0) ? Wq : (z == 1) ? Wk : (z == 2) ? Wv : Wo;
    u16* out = WT + (size_t)z * 512 * 512;
    const int tx = threadIdx.x, ty = threadIdx.y;
    const int k0 = blockIdx.y * 32, n0 = blockIdx.x * 32;
#pragma unroll
    for (int p = 0; p < 4; ++p)
        t[ty + 8 * p][tx] = W[(size_t)(k0 + ty + 8 * p) * 512 + n0 + tx];
    __syncthreads();
#pragma unroll
    for (int p = 0; p < 4; ++p) {
        const int n = n0 + ty + 8 * p;
        out[(size_t)n * 512 + k0 + tx] = f2bf(t[tx][ty + 8 * p]);
    }
}

// ---------------------------------------------------------------------------
// Kernel 1: convert q,k fp32 -> bf16 (row-major, same layout)
// ---------------------------------------------------------------------------
__global__ __launch_bounds__(256) void qkconv(const float* q, const float* k, u16* qb, u16* kb) {
    const size_t n4 = (size_t)8192 * 512 / 4;
    const size_t stride = (size_t)gridDim.x * 256;
    for (size_t i = (size_t)blockIdx.x * 256 + threadIdx.x; i < 2 * n4; i += stride) {
        const float4 v = (i < n4) ? ((const float4*)q)[i] : ((const float4*)k)[i - n4];
        u16x4 o;
        o[0] = f2bf(v.x); o[1] = f2bf(v.y); o[2] = f2bf(v.z); o[3] = f2bf(v.w);
        if (i < n4) ((u16x4*)qb)[i] = o; else ((u16x4*)kb)[i - n4] = o;
    }
}

// ---------------------------------------------------------------------------
// Kernel 1b: per-head transpose of vw: [B,L,H*64] bf16 -> vt [B*H][64 dk][1024 L]
// ---------------------------------------------------------------------------
__global__ __launch_bounds__(256) void vtrans(const u16* vw, u16* vt) {
    __shared__ u16 t[64][72];
    const int l0 = blockIdx.x * 64, h = blockIdx.y, b = blockIdx.z;
    const int tid = threadIdx.x;
    {
        const int r = tid >> 2, c16 = (tid & 3) * 16;
        const u16* src = vw + (size_t)(b * 1024 + l0 + r) * 512 + h * 64 + c16;
        *(u16x8*)(&t[r][c16])     = *(const u16x8*)(src);
        *(u16x8*)(&t[r][c16 + 8]) = *(const u16x8*)(src + 8);
    }
    __syncthreads();
    {
        const int dk = tid >> 2, lc = (tid & 3) * 16;
        u16x8 a0, a1;
#pragma unroll
        for (int e = 0; e < 8; ++e) { a0[e] = t[lc + e][dk]; a1[e] = t[lc + 8 + e][dk]; }
        u16* dst = vt + ((size_t)(b * 8 + h) * 64 + dk) * 1024 + l0 + lc;
        *(u16x8*)dst       = a0;
        *(u16x8*)(dst + 8) = a1;
    }
}

// ---------------------------------------------------------------------------
// GEMM core (all-bf16 inputs): C(8192 x 512) = A @ B + bias
// m97-style: global_load_lds dwordx4 staging into linear [128][64] LDS.
// ---------------------------------------------------------------------------
template <bool C_F32>
__device__ __forceinline__ void gemm_core(const u16* A, const u16* Bt,
                                          const float* bias, void* Cp,
                                          int bm, int bn) {
    __shared__ u16 As[128 * 64];
    __shared__ u16 Bs[128 * 64];
    const int tid  = threadIdx.x;
    const int lane = tid & 63;
    const int w    = tid >> 6;
    const int wm   = (w >> 1) * 64;
    const int wn   = (w & 1) * 64;
    const int col  = lane & 15;
    const int quad = lane >> 4;
    const int srow = lane >> 3;          // 0..7 within chunk
    const int scol = (lane & 7) * 8;     // u16 col within BK=64

    f32x4 acc[4][4] = {};

    for (int kt = 0; kt < 512; kt += 64) {
        __syncthreads();
#pragma unroll
        for (int p = 0; p < 4; ++p) {
            const int c  = w * 4 + p;        // 16 chunks of 1024B per tile
            const int gr = c * 8 + srow;
            gload_lds16(A  + (size_t)(bm * 128 + gr) * 512 + kt + scol, As + c * 512);
            gload_lds16(Bt + (size_t)(bn * 128 + gr) * 512 + kt + scol, Bs + c * 512);
        }
        __syncthreads();   // compiler drains vmcnt(0) here -> LDS tile ready
#pragma unroll
        for (int ks = 0; ks < 2; ++ks) {
            const int k0 = ks * 32 + quad * 8;
            bf16x8 af[4], bfr[4];
#pragma unroll
            for (int i = 0; i < 4; ++i)
                af[i] = __builtin_bit_cast(bf16x8, *(const u16x8*)(As + (wm + i * 16 + col) * 64 + k0));
#pragma unroll
            for (int j = 0; j < 4; ++j)
                bfr[j] = __builtin_bit_cast(bf16x8, *(const u16x8*)(Bs + (wn + j * 16 + col) * 64 + k0));
#pragma unroll
            for (int i = 0; i < 4; ++i)
#pragma unroll
                for (int j = 0; j < 4; ++j)
                    acc[i][j] = MFMA16(af[i], bfr[j], acc[i][j]);
        }
    }
#pragma unroll
    for (int j = 0; j < 4; ++j) {
        const int gn = bn * 128 + wn + j * 16 + col;
        const float bv = bias[gn];
#pragma unroll
        for (int i = 0; i < 4; ++i) {
#pragma unroll
            for (int r = 0; r < 4; ++r) {
                const int gm = bm * 128 + wm + i * 16 + quad * 4 + r;
                const float val = acc[i][j][r] + bv;
                if (C_F32) ((float*)Cp)[(size_t)gm * 512 + gn] = val;
                else       ((u16*)Cp)[(size_t)gm * 512 + gn]   = f2bf(val);
            }
        }
    }
}

// grid (64,4,3): z=0 qw=qb@Wq+bq, z=1 kw=kb@Wk+bk, z=2 vw=qb@Wv+bv (reference bug)
__global__ __launch_bounds__(256, 3) void qkv_gemm(const u16* qb, const u16* kb, const u16* WT,
                                                   const float* bq, const float* bk, const float* bv,
                                                   u16* out) {
    const int z = blockIdx.z;
    const u16* A      = (z == 1) ? kb : qb;
    const u16* B      = WT + (size_t)z * 512 * 512;
    const float* bias = (z == 0) ? bq : (z == 1) ? bk : bv;
    u16* C            = out + (size_t)z * 8192 * 512;
    gemm_core<false>(A, B, bias, C, blockIdx.x, blockIdx.y);
}

__global__ __launch_bounds__(256, 3) void out_gemm(const u16* ctx, const u16* WoT,
                                                   const float* bo, float* out) {
    gemm_core<true>(ctx, WoT, bo, out, blockIdx.x, blockIdx.y);
}

// ---------------------------------------------------------------------------
// Kernel 2: attention. grid (64 bh, 8 qtiles) -- bh fast so all q-tiles of a
// head share an XCD (K/V L2-resident). 512 threads (8 waves), wave owns 16 Q
// rows. SWAPPED QK^T: s = mfma(K, Q) -> S^T, so each lane holds 4 CONSECUTIVE
// keys of one q-row: P converts via paired bf16 casts (v_cvt_pk_bf16_f32) and
// writes as ds_write_b64 (conflict-free); row-sum reduce is 2 shuffles.
// Attn stores: 2 rows x 128 cols per instr = 512B contiguous segments, nt hint.
// ---------------------------------------------------------------------------
__global__ __launch_bounds__(512, 4) void attn_kernel(const u16* qw, const u16* kw, const u16* vt,
                                                      float* attn_out, u16* ctx) {
    __shared__ u16 Ks[128 * 72];       // [key][dk]   18432 B
    __shared__ u16 Vs[64 * 136];       // [dk][key]   17408 B
    __shared__ u16 Ps[8][16 * 136];    // per-wave [qrow][key] 34816 B  (total 70656 B)

    const int bh  = blockIdx.x;
    const int qt  = blockIdx.y;
    const int b   = bh >> 3, h = bh & 7;
    const int tid = threadIdx.x;
    const int lane = tid & 63, w = tid >> 6;
    const int col = lane & 15, quad = lane >> 4;
    const int wq  = w * 16;
    const float scale = 0.125f;

    const size_t headbase = (size_t)b * (1024 * 512) + (size_t)h * 64;
    const u16* vh = vt + (size_t)bh * (64 * 1024);

    // staging addressing
    const int krow = tid >> 2, koff = (tid & 3) * 16;   // 128 rows x 64 dk
    const int vrow = tid >> 3, voff = (tid & 7) * 16;   // 64 rows x 128 keys
    const u16* kbase = kw + headbase + (size_t)krow * 512 + koff;
    const u16* vbase = vh + (size_t)vrow * 1024 + voff;

    // Q fragment in registers (B-operand: row=lane&15=qrow, k=quad*8+e)
    bf16x8 qf[2];
    {
        const u16* qp = qw + headbase + (size_t)(qt * 128 + wq + col) * 512 + quad * 8;
        qf[0] = __builtin_bit_cast(bf16x8, *(const u16x8*)qp);
        qf[1] = __builtin_bit_cast(bf16x8, *(const u16x8*)(qp + 32));
    }

    float l_acc = 0.f;   // partial row-sum for q-row (lane&15), keys of this quad

    // ---------------- pass 1: row sumexp ----------------
    u16x8 rk0 = *(const u16x8*)kbase;
    u16x8 rk1 = *(const u16x8*)(kbase + 8);
    for (int kt = 0; kt < 8; ++kt) {
        __syncthreads();                       // waves done reading prev tile; loads drained
        *(u16x8*)(Ks + krow * 72 + koff)     = rk0;
        *(u16x8*)(Ks + krow * 72 + koff + 8) = rk1;
        __syncthreads();                       // tile visible
        if (kt < 7) {                          // prefetch next tile: in flight across compute
            const u16* kp = kbase + (size_t)(kt + 1) * (128 * 512);
            rk0 = *(const u16x8*)kp;
            rk1 = *(const u16x8*)(kp + 8);
        }
        f32x4 s[8] = {};
#pragma unroll
        for (int ks = 0; ks < 2; ++ks) {
            const int k0 = ks * 32 + quad * 8;
#pragma unroll
            for (int j = 0; j < 8; ++j) {
                const bf16x8 kf = __builtin_bit_cast(bf16x8,
                    *(const u16x8*)(Ks + (j * 16 + col) * 72 + k0));
                s[j] = MFMA16(kf, qf[ks], s[j]);   // SWAPPED: S^T
            }
        }
#pragma unroll
        for (int j = 0; j < 8; ++j)
#pragma unroll
            for (int r = 0; r < 4; ++r)
                l_acc += __expf(s[j][r] * scale);
    }

    float rinv;
    {
        float l = l_acc;
        l += __shfl_xor(l, 16); l += __shfl_xor(l, 32);   // sum the 4 quads
        rinv = 1.0f / l;
    }

    f32x4 o[4] = {};

    // ---------------- pass 2 ----------------
    rk0 = *(const u16x8*)kbase;
    rk1 = *(const u16x8*)(kbase + 8);
    u16x8 rv0 = *(const u16x8*)vbase;
    u16x8 rv1 = *(const u16x8*)(vbase + 8);
    for (int kt = 0; kt < 8; ++kt) {
        __syncthreads();
        *(u16x8*)(Ks + krow * 72 + koff)      = rk0;
        *(u16x8*)(Ks + krow * 72 + koff + 8)  = rk1;
        *(u16x8*)(Vs + vrow * 136 + voff)     = rv0;
        *(u16x8*)(Vs + vrow * 136 + voff + 8) = rv1;
        __syncthreads();
        if (kt < 7) {
            const u16* kp = kbase + (size_t)(kt + 1) * (128 * 512);
            rk0 = *(const u16x8*)kp;
            rk1 = *(const u16x8*)(kp + 8);
            const u16* vp = vbase + (kt + 1) * 128;
            rv0 = *(const u16x8*)vp;
            rv1 = *(const u16x8*)(vp + 8);
        }
        u16* pw = &Ps[w][0];
#pragma unroll
        for (int half = 0; half < 2; ++half) {
            f32x4 s[4] = {};
#pragma unroll
            for (int ks = 0; ks < 2; ++ks) {
                const int k0 = ks * 32 + quad * 8;
#pragma unroll
                for (int j = 0; j < 4; ++j) {
                    const bf16x8 kf = __builtin_bit_cast(bf16x8,
                        *(const u16x8*)(Ks + (half * 64 + j * 16 + col) * 72 + k0));
                    s[j] = MFMA16(kf, qf[ks], s[j]);   // SWAPPED: S^T
                }
            }
            // lane holds keys (half*64 + j*16 + quad*4 + r) of q-row (col):
            // 4 consecutive keys -> packed cvt + single ds_write_b64 per j
#pragma unroll
            for (int j = 0; j < 4; ++j) {
                u16x4 pk;
                pk[0] = bfc(__expf(s[j][0] * scale) * rinv);
                pk[1] = bfc(__expf(s[j][1] * scale) * rinv);
                pk[2] = bfc(__expf(s[j][2] * scale) * rinv);
                pk[3] = bfc(__expf(s[j][3] * scale) * rinv);
                *(u16x4*)(pw + col * 136 + half * 64 + j * 16 + quad * 4) = pk;
            }
        }
        // attn stores: per instr 2 rows x 32 lanes x 16B = two 512B segments
        {
            const int r2 = lane >> 5;            // 0..1
            const int c0 = (lane & 31) * 4;      // f32 col
            float* ao = attn_out + ((size_t)bh * 1024 + (size_t)(qt * 128 + wq)) * 1024
                        + (size_t)kt * 128;
#pragma unroll
            for (int it = 0; it < 8; ++it) {
                const int row = it * 2 + r2;
                const u16x4 pv = *(const u16x4*)(pw + row * 136 + c0);
                f32x4 f;
                f[0] = bf2f(pv[0]); f[1] = bf2f(pv[1]); f[2] = bf2f(pv[2]); f[3] = bf2f(pv[3]);
                __builtin_nontemporal_store(f, (f32x4*)(ao + (size_t)row * 1024 + c0));
            }
        }
        // PV: o[m][dk] += P[m][key] * V[key][dk], 128 keys = 4 k-slices
#pragma unroll
        for (int ks = 0; ks < 4; ++ks) {
            const int k0 = ks * 32 + quad * 8;
            const bf16x8 pf = __builtin_bit_cast(bf16x8, *(const u16x8*)(pw + col * 136 + k0));
#pragma unroll
            for (int j = 0; j < 4; ++j) {
                const bf16x8 vf = __builtin_bit_cast(bf16x8,
                    *(const u16x8*)(Vs + (j * 16 + col) * 136 + k0));
                o[j] = MFMA16(pf, vf, o[j]);
            }
        }
    }

    // ctx (bf16) at head slice
#pragma unroll
    for (int j = 0; j < 4; ++j)
#pragma unroll
        for (int r = 0; r < 4; ++r) {
            const int qg = qt * 128 + wq + quad * 4 + r;
            ctx[(size_t)(b * 1024 + qg) * 512 + h * 64 + j * 16 + col] = f2bf(o[j][r]);
        }
}

// ---------------------------------------------------------------------------
extern "C" void kernel_launch(void* const* d_in, const int* in_sizes, int n_in,
                              void* d_out, int out_size, void* d_ws, size_t ws_size,
                              hipStream_t stream) {
    (void)in_sizes; (void)n_in; (void)out_size; (void)ws_size;
    const float* q  = (const float*)d_in[0];
    const float* k  = (const float*)d_in[1];
    // d_in[2] = v : unused (reference bug applies Wv to q)
    const float* Wq = (const float*)d_in[3];
    const float* bq = (const float*)d_in[4];
    const float* Wk = (const float*)d_in[5];
    const float* bk = (const float*)d_in[6];
    const float* Wv = (const float*)d_in[7];
    const float* bv = (const float*)d_in[8];
    const float* Wo = (const float*)d_in[9];
    const float* bo = (const float*)d_in[10];

    float* out  = (float*)d_out;                              // (8,1024,512)
    float* attn = (float*)d_out + (size_t)8 * 1024 * 512;     // (8,8,1024,1024)

    // workspace layout
    char* ws = (char*)d_ws;
    u16* WT  = (u16*)ws;                                       // 2 MB
    u16* qb  = (u16*)(ws + (size_t)2 * 1024 * 1024);           // 8 MB
    u16* kb  = qb + (size_t)8192 * 512;                        // 8 MB
    u16* qkv = kb + (size_t)8192 * 512;                        // 32 MB (qw,kw,vw,ctx)
    u16* qw  = qkv;
    u16* kw  = qkv + (size_t)8192 * 512;
    u16* vw  = qkv + (size_t)2 * 8192 * 512;
    u16* ctx = qkv + (size_t)3 * 8192 * 512;
    u16* vt  = qkv + (size_t)4 * 8192 * 512;                   // 8 MB transposed V

    wtrans     <<<dim3(16, 16, 4), dim3(32, 8), 0, stream>>>(Wq, Wk, Wv, Wo, WT);
    qkconv     <<<dim3(2048),      256,          0, stream>>>(q, k, qb, kb);
    qkv_gemm   <<<dim3(64, 4, 3),  256,          0, stream>>>(qb, kb, WT, bq, bk, bv, qkv);
    vtrans     <<<dim3(16, 8, 8),  256,          0, stream>>>(vw, vt);
    attn_kernel<<<dim3(64, 8),     512,          0, stream>>>(qw, kw, vt, attn, ctx);
    out_gemm   <<<dim3(64, 4),     256,          0, stream>>>(ctx, WT + (size_t)3 * 512 * 512, bo, out);
}